// Round 3
// baseline (767.442 us; speedup 1.0000x reference)
//
#include <hip/hip_runtime.h>
#include <math.h>

#define NCLS 31
#define B 4096
#define D 512
#define N 8192
#define BT 128
#define NT (N / BT)               // 64 tiles per dim
#define NBLK (NT * (NT + 1) / 2)  // 2080 upper-tri blocks
#define BKB 64                    // bf16 K-chunk per iteration
#define NITER 24                  // K=1536 effective (hi|lo|hi vs hi|hi|lo)

// ws float layout (header, all below Xc at byte 65536)
#define WS_SUMSQB 0      // 8 bucketed sumsq accumulators
#define WS_ACC    8
#define WS_NBT    9      // -(n^2-n)/(4*sumL2) = -1/(16*b')
#define WS_SL     10     // scale * lamb
#define WS_CNT    11     // int done-counter
#define WS_SVAL   16     // 32: source class value m_c/count_c
#define WS_TVAL   48     // 32: target class value -m_c/colsum_c
#define WS_COLP   128    // 8*512 bucketed column-sum partials
#define WS_SQ     4224   // 8192 row squared norms
#define WS_XC_BYTES 65536  // Xc: bf16 [8192][1024] (hi|lo), 16 MB

typedef __attribute__((ext_vector_type(8))) short bf16x8;
typedef __attribute__((ext_vector_type(4))) float f32x4;
typedef __attribute__((ext_vector_type(8))) unsigned short u16x8;

__device__ __forceinline__ unsigned short f2bf(float x) {
  unsigned u = __float_as_uint(x);
  u += 0x7fffu + ((u >> 16) & 1u);  // RNE (inputs finite)
  return (unsigned short)(u >> 16);
}
__device__ __forceinline__ float bf2f(unsigned short b) {
  return __uint_as_float(((unsigned)b) << 16);
}

// XOR-swizzled fragment read: logical (row r, 8-elem granule g) -> 16B
__device__ __forceinline__ bf16x8 frag_read(const short* tile, int r, int g) {
  int phys = r * 8 + (g ^ (r & 7));
  return *(const bf16x8*)(tile + phys * 8);
}

// fused: bf16 hi/lo convert + row sumsq + bucketed column sums
__global__ void k_pre(const float* __restrict__ src, const float* __restrict__ tgt,
                      float* __restrict__ wsf, unsigned short* __restrict__ Xc) {
  __shared__ float rowbuf[4][512];
  __shared__ float ssq[4];
  const int tid = threadIdx.x, wv = tid >> 6, lane = tid & 63;
  const int row = blockIdx.x * 4 + wv;
  const float* p = (row < B) ? src + (size_t)row * D : tgt + (size_t)(row - B) * D;
  float4 a = ((const float4*)p)[lane], b = ((const float4*)p)[lane + 64];
  ushort4 ha, la, hb, lb;
  ha.x = f2bf(a.x); la.x = f2bf(a.x - bf2f(ha.x));
  ha.y = f2bf(a.y); la.y = f2bf(a.y - bf2f(ha.y));
  ha.z = f2bf(a.z); la.z = f2bf(a.z - bf2f(ha.z));
  ha.w = f2bf(a.w); la.w = f2bf(a.w - bf2f(ha.w));
  hb.x = f2bf(b.x); lb.x = f2bf(b.x - bf2f(hb.x));
  hb.y = f2bf(b.y); lb.y = f2bf(b.y - bf2f(hb.y));
  hb.z = f2bf(b.z); lb.z = f2bf(b.z - bf2f(hb.z));
  hb.w = f2bf(b.w); lb.w = f2bf(b.w - bf2f(hb.w));
  size_t rb8 = (size_t)row * 1024;
  *(ushort4*)(Xc + rb8 + lane * 4)       = ha;   // hi cols 0..255
  *(ushort4*)(Xc + rb8 + 256 + lane * 4) = hb;   // hi cols 256..511
  *(ushort4*)(Xc + rb8 + 512 + lane * 4) = la;   // lo cols 0..255
  *(ushort4*)(Xc + rb8 + 768 + lane * 4) = lb;   // lo cols 256..511
  float s = a.x*a.x + a.y*a.y + a.z*a.z + a.w*a.w
          + b.x*b.x + b.y*b.y + b.z*b.z + b.w*b.w;
  *(float4*)&rowbuf[wv][lane * 4] = a;
  *(float4*)&rowbuf[wv][256 + lane * 4] = b;
  #pragma unroll
  for (int off = 32; off; off >>= 1) s += __shfl_down(s, off);
  if (lane == 0) { wsf[WS_SQ + row] = s; ssq[wv] = s; }
  __syncthreads();
  float c0 = rowbuf[0][tid] + rowbuf[1][tid] + rowbuf[2][tid] + rowbuf[3][tid];
  float c1 = rowbuf[0][tid+256] + rowbuf[1][tid+256] + rowbuf[2][tid+256] + rowbuf[3][tid+256];
  int bkt = (blockIdx.x & 7) * 512;
  atomicAdd(&wsf[WS_COLP + bkt + tid], c0);
  atomicAdd(&wsf[WS_COLP + bkt + tid + 256], c1);
  if (tid == 0)
    atomicAdd(&wsf[WS_SUMSQB + (blockIdx.x & 7)], ssq[0] + ssq[1] + ssq[2] + ssq[3]);
}

// fused: class stats (hist/argmax/logit-colsum) + bandwidth + scale*lamb
__global__ void k_stats(const int* __restrict__ label, const float* __restrict__ logits,
                        const int* __restrict__ iter_p, float* __restrict__ wsf) {
  __shared__ int cnt[NCLS];
  __shared__ float csum[NCLS];
  __shared__ unsigned presT;
  __shared__ float part[4];
  int tid = threadIdx.x;
  if (tid < NCLS) { cnt[tid] = 0; csum[tid] = 0.f; }
  if (tid == 0) presT = 0u;
  __syncthreads();
  float acc[NCLS];
  #pragma unroll
  for (int c = 0; c < NCLS; c++) acc[c] = 0.f;
  for (int r = tid; r < B; r += 256) {
    atomicAdd(&cnt[label[r]], 1);
    const float* lp = logits + (size_t)r * NCLS;
    float mx = -1e30f; int am = 0;
    #pragma unroll
    for (int c = 0; c < NCLS; c++) {
      float v = lp[c];
      acc[c] += v;
      if (v > mx) { mx = v; am = c; }  // strict >: first max, matches argmax
    }
    atomicOr(&presT, 1u << am);
  }
  #pragma unroll
  for (int c = 0; c < NCLS; c++) atomicAdd(&csum[c], acc[c]);
  // column-sum squared-norm from buckets
  float v = 0.f;
  for (int c = tid; c < 512; c += 256) {
    float t = 0.f;
    #pragma unroll
    for (int bk = 0; bk < 8; bk++) t += wsf[WS_COLP + bk * 512 + c];
    v += t * t;
  }
  #pragma unroll
  for (int off = 32; off; off >>= 1) v += __shfl_down(v, off);
  if ((tid & 63) == 0) part[tid >> 6] = v;
  __syncthreads();
  if (tid == 0) {
    int cm = 0;
    for (int c = 0; c < NCLS; c++) {
      bool m = (cnt[c] > 0) && ((presT >> c) & 1u);
      if (m) cm++;
      wsf[WS_SVAL + c] = m ? 1.f / (float)cnt[c] : 0.f;
      float cs = csum[c]; if (cs == 0.f) cs = 100.f;
      wsf[WS_TVAL + c] = m ? -1.f / cs : 0.f;
    }
    wsf[WS_SVAL + 31] = 0.f; wsf[WS_TVAL + 31] = 0.f;
    float scale = (cm > 0) ? 1.f / (float)cm : 0.f;
    float pp = (float)iter_p[0] / 1000.f;
    float lamb = 2.f / (1.f + __expf(-pp)) - 1.f;
    wsf[WS_SL] = scale * lamb;
    double colnorm2 = (double)part[0] + part[1] + part[2] + part[3];
    double sumsq = 0.0;
    for (int bk = 0; bk < 8; bk++) sumsq += (double)wsf[WS_SUMSQB + bk];
    double sumL2 = 2.0 * (double)N * sumsq - 2.0 * colnorm2;
    wsf[WS_NBT] = (float)(-((double)N * (double)N - (double)N) / (4.0 * sumL2));
  }
}

// loss = sum_{tile} mult * K(d2) .* (Q_i Q_j^T), bf16 MFMA hi/lo, reg-prefetch pipeline
__launch_bounds__(256, 3)
__global__ void k_main(const unsigned short* __restrict__ Xc,
                       const int* __restrict__ label, const float* __restrict__ logits,
                       float* __restrict__ wsf, float* __restrict__ out) {
  __shared__ __align__(16) short tileA[BT * BKB];   // 16 KB, XOR-swizzled
  __shared__ __align__(16) short tileB[BT * BKB];   // 16 KB
  __shared__ float sqi[BT], sqj[BT];
  __shared__ float red[4];

  // triangular block decode: bi <= bj, S(bi) = bi*(129-bi)/2
  int bid = blockIdx.x;
  int bi = (int)(64.5f - sqrtf(64.5f * 64.5f - 2.0f * (float)bid));
  while (bi > 0 && bid < (bi * (129 - bi)) / 2) --bi;
  while (bid >= ((bi + 1) * (128 - bi)) / 2) ++bi;
  int bj = bi + (bid - (bi * (129 - bi)) / 2);
  const int i0 = bi * BT, j0 = bj * BT;
  const float mult = (bi == bj) ? 1.f : 2.f;

  const int tid = threadIdx.x;
  const int w = tid >> 6, lane = tid & 63;
  const int woff_m = (w >> 1) * 64, woff_n = (w & 1) * 64;
  const int fr = lane & 15, fg = lane >> 4;       // fragment row / k-group
  const int srow = lane >> 3;                     // staging row-in-8
  const int sgrp = (lane & 7) ^ srow;             // staging logical granule

  if (tid < 128) sqi[tid] = wsf[WS_SQ + i0 + tid];
  else           sqj[tid - 128] = wsf[WS_SQ + j0 + (tid - 128)];
  const float nbt = wsf[WS_NBT];

  f32x4 acc[4][4];
  #pragma unroll
  for (int mt = 0; mt < 4; mt++)
    #pragma unroll
    for (int nt = 0; nt < 4; nt++) acc[mt][nt] = (f32x4){0.f, 0.f, 0.f, 0.f};

  // register prefetch pipeline: load iter 0
  float4 ra[4], rb[4];
  #pragma unroll
  for (int q = 0; q < 4; ++q) {
    const int rl = (w * 4 + q) * 8 + srow;
    ra[q] = *(const float4*)(Xc + (size_t)(i0 + rl) * 1024 + sgrp * 8);
    rb[q] = *(const float4*)(Xc + (size_t)(j0 + rl) * 1024 + sgrp * 8);
  }

  for (int it = 0; it < NITER; ++it) {
    __syncthreads();   // prev-iter LDS reads complete
    #pragma unroll
    for (int q = 0; q < 4; ++q) {
      *(float4*)(tileA + (w * 4 + q) * 512 + lane * 8) = ra[q];
      *(float4*)(tileB + (w * 4 + q) * 512 + lane * 8) = rb[q];
    }
    __syncthreads();
    if (it + 1 < NITER) {
      const int itn = it + 1;
      // segment remap: A' = [hi|lo|hi], B' = [hi|hi|lo] over Xc rows [hi(512)|lo(512)]
      const int offA = (itn < 16 ? itn : itn - 16) * BKB;
      const int offB = (itn < 8 ? itn : itn - 8) * BKB;
      #pragma unroll
      for (int q = 0; q < 4; ++q) {
        const int rl = (w * 4 + q) * 8 + srow;
        ra[q] = *(const float4*)(Xc + (size_t)(i0 + rl) * 1024 + offA + sgrp * 8);
        rb[q] = *(const float4*)(Xc + (size_t)(j0 + rl) * 1024 + offB + sgrp * 8);
      }
    }
    #pragma unroll
    for (int ks = 0; ks < 2; ++ks) {
      bf16x8 af[4], bfr[4];
      #pragma unroll
      for (int mt = 0; mt < 4; mt++)
        af[mt] = frag_read(tileA, woff_m + mt * 16 + fr, ks * 4 + fg);
      #pragma unroll
      for (int nt = 0; nt < 4; nt++)
        bfr[nt] = frag_read(tileB, woff_n + nt * 16 + fr, ks * 4 + fg);
      #pragma unroll
      for (int mt = 0; mt < 4; mt++)
        #pragma unroll
        for (int nt = 0; nt < 4; nt++)
          acc[mt][nt] = __builtin_amdgcn_mfma_f32_16x16x32_bf16(
              af[mt], bfr[nt], acc[mt][nt], 0, 0, 0);
    }
  }

  // acc -> multi-band Gaussian kernel: t + t^2 + t^4 + t^8 + t^16
  float sj4[4], si16[4][4];
  #pragma unroll
  for (int nt = 0; nt < 4; nt++) sj4[nt] = sqj[woff_n + nt * 16 + fr];
  #pragma unroll
  for (int mt = 0; mt < 4; mt++)
    #pragma unroll
    for (int t = 0; t < 4; t++) si16[mt][t] = sqi[woff_m + mt * 16 + fg * 4 + t];
  #pragma unroll
  for (int mt = 0; mt < 4; mt++)
    #pragma unroll
    for (int nt = 0; nt < 4; nt++)
      #pragma unroll
      for (int t = 0; t < 4; t++) {
        float d2 = fmaxf(si16[mt][t] + sj4[nt] - 2.f * acc[mt][nt][t], 0.f);
        float e1 = __expf(d2 * nbt);
        float e2 = e1 * e1, e4 = e2 * e2, e8 = e4 * e4, e16 = e8 * e8;
        acc[mt][nt][t] = ((e16 + e8) + (e4 + e2)) + e1;
      }

  // build Q tiles (hi|lo bf16) into reused LDS, same swizzle
  __syncthreads();
  {
    const int t = tid & 127;
    short* qt = (tid < 128) ? tileA : tileB;
    const int gq = ((tid < 128) ? i0 : j0) + t;
    const int lab = (gq < B) ? label[gq] : -1;
    const float sv = (gq < B) ? wsf[WS_SVAL + lab] : 0.f;
    const float* lp = (gq < B) ? (const float*)0 : logits + (size_t)(gq - B) * NCLS;
    #pragma unroll
    for (int g = 0; g < 8; ++g) {
      u16x8 pack = (u16x8){0,0,0,0,0,0,0,0};
      const int cbase = (g & 3) * 8;
      if (gq < B) {
        if (lab >= cbase && lab < cbase + 8) {
          unsigned short h = f2bf(sv);
          pack[lab - cbase] = (g < 4) ? h : f2bf(sv - bf2f(h));
        }
      } else {
        #pragma unroll
        for (int jc = 0; jc < 8; ++jc) {
          int cc = cbase + jc;
          if (cc < NCLS) {
            float v = lp[cc] * wsf[WS_TVAL + cc];
            unsigned short h = f2bf(v);
            pack[jc] = (g < 4) ? h : f2bf(v - bf2f(h));
          }
        }
      }
      int phys = t * 8 + (g ^ (t & 7));
      *(u16x8*)(qt + phys * 8) = pack;
    }
  }
  __syncthreads();

  // Gram via MFMA (K=96: hi.hi + lo.hi + hi.lo), elementwise-dot with kernel values
  float part = 0.f;
  #pragma unroll
  for (int ch = 0; ch < 3; ++ch) {
    const int ab = (ch == 1) ? 4 : 0, bb = (ch == 2) ? 4 : 0;
    bf16x8 af[4], bfr[4];
    #pragma unroll
    for (int mt = 0; mt < 4; mt++)
      af[mt] = frag_read(tileA, woff_m + mt * 16 + fr, ab + fg);
    #pragma unroll
    for (int nt = 0; nt < 4; nt++)
      bfr[nt] = frag_read(tileB, woff_n + nt * 16 + fr, bb + fg);
    #pragma unroll
    for (int mt = 0; mt < 4; mt++)
      #pragma unroll
      for (int nt = 0; nt < 4; nt++) {
        f32x4 z = (f32x4){0.f, 0.f, 0.f, 0.f};
        f32x4 g = __builtin_amdgcn_mfma_f32_16x16x32_bf16(af[mt], bfr[nt], z, 0, 0, 0);
        part += acc[mt][nt].x * g.x + acc[mt][nt].y * g.y
              + acc[mt][nt].z * g.z + acc[mt][nt].w * g.w;
      }
  }
  part *= mult;
  #pragma unroll
  for (int off = 32; off; off >>= 1) part += __shfl_down(part, off);
  if (lane == 0) red[w] = part;
  __syncthreads();
  if (tid == 0) {
    atomicAdd(&wsf[WS_ACC], red[0] + red[1] + red[2] + red[3]);
    __threadfence();
    int old = atomicAdd((int*)&wsf[WS_CNT], 1);
    if (old == NBLK - 1) {
      float total = atomicAdd(&wsf[WS_ACC], 0.f);  // atomic read of final sum
      out[0] = total * wsf[WS_SL];
    }
  }
}

extern "C" void kernel_launch(void* const* d_in, const int* in_sizes, int n_in,
                              void* d_out, int out_size, void* d_ws, size_t ws_size,
                              hipStream_t stream) {
  const float* src    = (const float*)d_in[0];
  const float* tgt    = (const float*)d_in[1];
  const int*   label  = (const int*)d_in[2];
  const float* logits = (const float*)d_in[3];
  const int*   iter_p = (const int*)d_in[4];
  float* wsf = (float*)d_ws;
  unsigned short* Xc = (unsigned short*)((char*)d_ws + WS_XC_BYTES);
  float* out = (float*)d_out;

  hipMemsetAsync(d_ws, 0, 20480, stream);   // zero scalars + bucket accumulators
  k_pre<<<N / 4, 256, 0, stream>>>(src, tgt, wsf, Xc);
  k_stats<<<1, 256, 0, stream>>>(label, logits, iter_p, wsf);
  k_main<<<NBLK, 256, 0, stream>>>(Xc, label, logits, wsf, out);
}

// Round 4
// 356.737 us; speedup vs baseline: 2.1513x; 2.1513x over previous
//
#include <hip/hip_runtime.h>
#include <math.h>

#define NCLS 31
#define B 4096
#define D 512
#define N 8192
#define BT 128
#define NT (N / BT)               // 64 tiles per dim
#define NBLK (NT * (NT + 1) / 2)  // 2080 upper-tri blocks
#define BKB 64                    // bf16 K-chunk per iteration
#define NITER 24                  // K=1536 effective (hi|lo|hi vs hi|hi|lo)

// ws float-index layout (all below Xc at byte 65536)
#define WS_SUMSQB 0      // 8 bucketed sumsq accumulators
#define WS_ACC    8
#define WS_NBT    9      // -(n^2-n)/(4*sumL2) = -1/(16*b')
#define WS_SL     10
#define WS_CNT    11     // int done-counter
#define WS_HIST   12     // 31 ints: label histogram
#define WS_PRES   43     // unsigned: target-present mask
#define WS_CSUM   44     // 31 floats: logit column sums
#define WS_SVAL   80     // 32
#define WS_TVAL   112    // 32
#define WS_COLP   256    // 8*512 bucketed column-sum partials
#define WS_SQ     4352   // 8192 row squared norms
#define WS_XC_BYTES 65536  // Xc: bf16 [8192][1024] (hi|lo), 16 MB

typedef __attribute__((ext_vector_type(8))) short bf16x8;
typedef __attribute__((ext_vector_type(4))) float f32x4;
typedef __attribute__((ext_vector_type(8))) unsigned short u16x8;

__device__ __forceinline__ unsigned short f2bf(float x) {
  unsigned u = __float_as_uint(x);
  u += 0x7fffu + ((u >> 16) & 1u);  // RNE (inputs finite)
  return (unsigned short)(u >> 16);
}
__device__ __forceinline__ float bf2f(unsigned short b) {
  return __uint_as_float(((unsigned)b) << 16);
}

__device__ __forceinline__ void async_lds16(const unsigned short* g, const short* l) {
  __builtin_amdgcn_global_load_lds(
      (const __attribute__((address_space(1))) unsigned int*)g,
      (__attribute__((address_space(3))) unsigned int*)l, 16, 0, 0);
}

// XOR-swizzled fragment read: logical (row r, 8-elem granule g) -> 16B
__device__ __forceinline__ bf16x8 frag_read(const short* tile, int r, int g) {
  int phys = r * 8 + (g ^ (r & 7));
  return *(const bf16x8*)(tile + phys * 8);
}

// fused: bf16 hi/lo convert + row sumsq + bucketed column sums
//        + (blocks 0..63) label/logits class stats via LDS-then-global atomics
__global__ void k_pre(const float* __restrict__ src, const float* __restrict__ tgt,
                      const int* __restrict__ label, const float* __restrict__ logits,
                      float* __restrict__ wsf, unsigned short* __restrict__ Xc) {
  __shared__ float rowbuf[4][512];
  __shared__ float ssq[4];
  __shared__ int lcnt[32];
  __shared__ float lcsum[32];
  __shared__ unsigned lpres;
  const int tid = threadIdx.x, wv = tid >> 6, lane = tid & 63;
  const bool statblk = (blockIdx.x < 64);
  if (statblk && tid < 32) { lcnt[tid] = 0; lcsum[tid] = 0.f; if (tid == 0) lpres = 0u; }
  const int row = blockIdx.x * 4 + wv;
  const float* p = (row < B) ? src + (size_t)row * D : tgt + (size_t)(row - B) * D;
  float4 a = ((const float4*)p)[lane], b = ((const float4*)p)[lane + 64];
  ushort4 ha, la, hb, lb;
  ha.x = f2bf(a.x); la.x = f2bf(a.x - bf2f(ha.x));
  ha.y = f2bf(a.y); la.y = f2bf(a.y - bf2f(ha.y));
  ha.z = f2bf(a.z); la.z = f2bf(a.z - bf2f(ha.z));
  ha.w = f2bf(a.w); la.w = f2bf(a.w - bf2f(ha.w));
  hb.x = f2bf(b.x); lb.x = f2bf(b.x - bf2f(hb.x));
  hb.y = f2bf(b.y); lb.y = f2bf(b.y - bf2f(hb.y));
  hb.z = f2bf(b.z); lb.z = f2bf(b.z - bf2f(hb.z));
  hb.w = f2bf(b.w); lb.w = f2bf(b.w - bf2f(hb.w));
  size_t rb8 = (size_t)row * 1024;
  *(ushort4*)(Xc + rb8 + lane * 4)       = ha;   // hi cols 0..255
  *(ushort4*)(Xc + rb8 + 256 + lane * 4) = hb;   // hi cols 256..511
  *(ushort4*)(Xc + rb8 + 512 + lane * 4) = la;   // lo cols 0..255
  *(ushort4*)(Xc + rb8 + 768 + lane * 4) = lb;   // lo cols 256..511
  float s = a.x*a.x + a.y*a.y + a.z*a.z + a.w*a.w
          + b.x*b.x + b.y*b.y + b.z*b.z + b.w*b.w;
  *(float4*)&rowbuf[wv][lane * 4] = a;
  *(float4*)&rowbuf[wv][256 + lane * 4] = b;
  #pragma unroll
  for (int off = 32; off; off >>= 1) s += __shfl_down(s, off);
  if (lane == 0) { wsf[WS_SQ + row] = s; ssq[wv] = s; }
  __syncthreads();
  float c0 = rowbuf[0][tid] + rowbuf[1][tid] + rowbuf[2][tid] + rowbuf[3][tid];
  float c1 = rowbuf[0][tid+256] + rowbuf[1][tid+256] + rowbuf[2][tid+256] + rowbuf[3][tid+256];
  int bkt = (blockIdx.x & 7) * 512;
  atomicAdd(&wsf[WS_COLP + bkt + tid], c0);
  atomicAdd(&wsf[WS_COLP + bkt + tid + 256], c1);
  if (tid == 0)
    atomicAdd(&wsf[WS_SUMSQB + (blockIdx.x & 7)], ssq[0] + ssq[1] + ssq[2] + ssq[3]);
  if (statblk) {
    if (tid < 64) {
      int r = blockIdx.x * 64 + tid;
      atomicAdd(&lcnt[label[r]], 1);
      const float* lp = logits + (size_t)r * NCLS;
      float mx = -1e30f; int am = 0;
      #pragma unroll
      for (int c = 0; c < NCLS; c++) {
        float v = lp[c];
        atomicAdd(&lcsum[c], v);
        if (v > mx) { mx = v; am = c; }  // strict >: first max, matches argmax
      }
      atomicOr(&lpres, 1u << am);
    }
    __syncthreads();
    if (tid < NCLS) {
      if (lcnt[tid]) atomicAdd((int*)&wsf[WS_HIST] + tid, lcnt[tid]);
      atomicAdd(&wsf[WS_CSUM + tid], lcsum[tid]);
    }
    if (tid == 0) atomicOr((unsigned*)&wsf[WS_PRES], lpres);
  }
}

// tiny single-block finalize: class values + bandwidth + scale*lamb
__global__ void k_stats(const int* __restrict__ iter_p, float* __restrict__ wsf) {
  __shared__ float part[4];
  int tid = threadIdx.x;
  // column-sum squared-norm from buckets
  float v = 0.f;
  for (int c = tid; c < 512; c += 256) {
    float t = 0.f;
    #pragma unroll
    for (int bk = 0; bk < 8; bk++) t += wsf[WS_COLP + bk * 512 + c];
    v += t * t;
  }
  #pragma unroll
  for (int off = 32; off; off >>= 1) v += __shfl_down(v, off);
  if ((tid & 63) == 0) part[tid >> 6] = v;
  __syncthreads();
  if (tid == 0) {
    unsigned presT = *(unsigned*)&wsf[WS_PRES];
    int cm = 0;
    for (int c = 0; c < NCLS; c++) {
      int cnt = ((int*)&wsf[WS_HIST])[c];
      bool m = (cnt > 0) && ((presT >> c) & 1u);
      if (m) cm++;
      wsf[WS_SVAL + c] = m ? 1.f / (float)cnt : 0.f;
      float cs = wsf[WS_CSUM + c]; if (cs == 0.f) cs = 100.f;
      wsf[WS_TVAL + c] = m ? -1.f / cs : 0.f;
    }
    wsf[WS_SVAL + 31] = 0.f; wsf[WS_TVAL + 31] = 0.f;
    float scale = (cm > 0) ? 1.f / (float)cm : 0.f;
    float pp = (float)iter_p[0] / 1000.f;
    float lamb = 2.f / (1.f + __expf(-pp)) - 1.f;
    wsf[WS_SL] = scale * lamb;
    double colnorm2 = (double)part[0] + part[1] + part[2] + part[3];
    double sumsq = 0.0;
    for (int bk = 0; bk < 8; bk++) sumsq += (double)wsf[WS_SUMSQB + bk];
    double sumL2 = 2.0 * (double)N * sumsq - 2.0 * colnorm2;
    wsf[WS_NBT] = (float)(-((double)N * (double)N - (double)N) / (4.0 * sumL2));
  }
}

// loss = sum_{tile} mult * K(d2) .* (Q_i Q_j^T), bf16 MFMA hi/lo (R2 staging structure)
__launch_bounds__(256, 3)
__global__ void k_main(const unsigned short* __restrict__ Xc,
                       const int* __restrict__ label, const float* __restrict__ logits,
                       float* __restrict__ wsf, float* __restrict__ out) {
  __shared__ __align__(16) short tileA[BT * BKB];   // 16 KB, XOR-swizzled
  __shared__ __align__(16) short tileB[BT * BKB];   // 16 KB
  __shared__ float sqi[BT], sqj[BT];
  __shared__ float red[4];

  // triangular block decode: bi <= bj, S(bi) = bi*(129-bi)/2
  int bid = blockIdx.x;
  int bi = (int)(64.5f - sqrtf(64.5f * 64.5f - 2.0f * (float)bid));
  while (bi > 0 && bid < (bi * (129 - bi)) / 2) --bi;
  while (bid >= ((bi + 1) * (128 - bi)) / 2) ++bi;
  int bj = bi + (bid - (bi * (129 - bi)) / 2);
  const int i0 = bi * BT, j0 = bj * BT;
  const float mult = (bi == bj) ? 1.f : 2.f;

  const int tid = threadIdx.x;
  const int w = tid >> 6, lane = tid & 63;
  const int woff_m = (w >> 1) * 64, woff_n = (w & 1) * 64;
  const int fr = lane & 15, fg = lane >> 4;       // fragment row / k-group
  const int srow = lane >> 3;                     // staging row-in-8
  const int sgrp = (lane & 7) ^ srow;             // staging logical granule

  if (tid < 128) sqi[tid] = wsf[WS_SQ + i0 + tid];
  else           sqj[tid - 128] = wsf[WS_SQ + j0 + (tid - 128)];
  const float nbt = wsf[WS_NBT];

  f32x4 acc[4][4];
  #pragma unroll
  for (int mt = 0; mt < 4; mt++)
    #pragma unroll
    for (int nt = 0; nt < 4; nt++) acc[mt][nt] = (f32x4){0.f, 0.f, 0.f, 0.f};

  for (int it = 0; it < NITER; ++it) {
    // segment remap: A' = [hi|lo|hi], B' = [hi|hi|lo] over Xc rows [hi(512)|lo(512)]
    const int offA = (it < 16 ? it : it - 16) * BKB;
    const int offB = (it < 8 ? it : it - 8) * BKB;
    __syncthreads();
    #pragma unroll
    for (int q = 0; q < 4; ++q) {
      const int inst = w * 4 + q;                  // 0..15, 8 rows each
      const int rl = inst * 8 + srow;              // local row 0..127
      async_lds16(Xc + (size_t)(i0 + rl) * 1024 + offA + sgrp * 8,
                  tileA + inst * 512);
      async_lds16(Xc + (size_t)(j0 + rl) * 1024 + offB + sgrp * 8,
                  tileB + inst * 512);
    }
    __syncthreads();
    #pragma unroll
    for (int ks = 0; ks < 2; ++ks) {
      bf16x8 af[4], bfr[4];
      #pragma unroll
      for (int mt = 0; mt < 4; mt++)
        af[mt] = frag_read(tileA, woff_m + mt * 16 + fr, ks * 4 + fg);
      #pragma unroll
      for (int nt = 0; nt < 4; nt++)
        bfr[nt] = frag_read(tileB, woff_n + nt * 16 + fr, ks * 4 + fg);
      #pragma unroll
      for (int mt = 0; mt < 4; mt++)
        #pragma unroll
        for (int nt = 0; nt < 4; nt++)
          acc[mt][nt] = __builtin_amdgcn_mfma_f32_16x16x32_bf16(
              af[mt], bfr[nt], acc[mt][nt], 0, 0, 0);
    }
  }

  // acc -> multi-band Gaussian kernel: t + t^2 + t^4 + t^8 + t^16
  float sj4[4], si16[4][4];
  #pragma unroll
  for (int nt = 0; nt < 4; nt++) sj4[nt] = sqj[woff_n + nt * 16 + fr];
  #pragma unroll
  for (int mt = 0; mt < 4; mt++)
    #pragma unroll
    for (int t = 0; t < 4; t++) si16[mt][t] = sqi[woff_m + mt * 16 + fg * 4 + t];
  #pragma unroll
  for (int mt = 0; mt < 4; mt++)
    #pragma unroll
    for (int nt = 0; nt < 4; nt++)
      #pragma unroll
      for (int t = 0; t < 4; t++) {
        float d2 = fmaxf(si16[mt][t] + sj4[nt] - 2.f * acc[mt][nt][t], 0.f);
        float e1 = __expf(d2 * nbt);
        float e2 = e1 * e1, e4 = e2 * e2, e8 = e4 * e4, e16 = e8 * e8;
        acc[mt][nt][t] = ((e16 + e8) + (e4 + e2)) + e1;
      }

  // build Q tiles (hi|lo bf16) into reused LDS, same swizzle
  __syncthreads();
  {
    const int t = tid & 127;
    short* qt = (tid < 128) ? tileA : tileB;
    const int gq = ((tid < 128) ? i0 : j0) + t;
    const int lab = (gq < B) ? label[gq] : -1;
    const float sv = (gq < B) ? wsf[WS_SVAL + lab] : 0.f;
    const float* lp = (gq < B) ? (const float*)0 : logits + (size_t)(gq - B) * NCLS;
    #pragma unroll
    for (int g = 0; g < 8; ++g) {
      u16x8 pack = (u16x8){0,0,0,0,0,0,0,0};
      const int cbase = (g & 3) * 8;
      if (gq < B) {
        if (lab >= cbase && lab < cbase + 8) {
          unsigned short h = f2bf(sv);
          pack[lab - cbase] = (g < 4) ? h : f2bf(sv - bf2f(h));
        }
      } else {
        #pragma unroll
        for (int jc = 0; jc < 8; ++jc) {
          int cc = cbase + jc;
          if (cc < NCLS) {
            float v = lp[cc] * wsf[WS_TVAL + cc];
            unsigned short h = f2bf(v);
            pack[jc] = (g < 4) ? h : f2bf(v - bf2f(h));
          }
        }
      }
      int phys = t * 8 + (g ^ (t & 7));
      *(u16x8*)(qt + phys * 8) = pack;
    }
  }
  __syncthreads();

  // Gram via MFMA (K=96: hi.hi + lo.hi + hi.lo), elementwise-dot with kernel values
  float part = 0.f;
  #pragma unroll
  for (int ch = 0; ch < 3; ++ch) {
    const int ab = (ch == 1) ? 4 : 0, bb = (ch == 2) ? 4 : 0;
    bf16x8 af[4], bfr[4];
    #pragma unroll
    for (int mt = 0; mt < 4; mt++)
      af[mt] = frag_read(tileA, woff_m + mt * 16 + fr, ab + fg);
    #pragma unroll
    for (int nt = 0; nt < 4; nt++)
      bfr[nt] = frag_read(tileB, woff_n + nt * 16 + fr, bb + fg);
    #pragma unroll
    for (int mt = 0; mt < 4; mt++)
      #pragma unroll
      for (int nt = 0; nt < 4; nt++) {
        f32x4 z = (f32x4){0.f, 0.f, 0.f, 0.f};
        f32x4 g = __builtin_amdgcn_mfma_f32_16x16x32_bf16(af[mt], bfr[nt], z, 0, 0, 0);
        part += acc[mt][nt].x * g.x + acc[mt][nt].y * g.y
              + acc[mt][nt].z * g.z + acc[mt][nt].w * g.w;
      }
  }
  part *= mult;
  #pragma unroll
  for (int off = 32; off; off >>= 1) part += __shfl_down(part, off);
  if (lane == 0) red[w] = part;
  __syncthreads();
  if (tid == 0) {
    atomicAdd(&wsf[WS_ACC], red[0] + red[1] + red[2] + red[3]);
    __threadfence();
    int old = atomicAdd((int*)&wsf[WS_CNT], 1);
    if (old == NBLK - 1) {
      __threadfence();
      float total = atomicAdd(&wsf[WS_ACC], 0.f);  // atomic read of final sum
      out[0] = total * wsf[WS_SL];
    }
  }
}

extern "C" void kernel_launch(void* const* d_in, const int* in_sizes, int n_in,
                              void* d_out, int out_size, void* d_ws, size_t ws_size,
                              hipStream_t stream) {
  const float* src    = (const float*)d_in[0];
  const float* tgt    = (const float*)d_in[1];
  const int*   label  = (const int*)d_in[2];
  const float* logits = (const float*)d_in[3];
  const int*   iter_p = (const int*)d_in[4];
  float* wsf = (float*)d_ws;
  unsigned short* Xc = (unsigned short*)((char*)d_ws + WS_XC_BYTES);
  float* out = (float*)d_out;

  hipMemsetAsync(d_ws, 0, 20480, stream);   // zero scalars + stat/bucket accumulators
  k_pre<<<N / 4, 256, 0, stream>>>(src, tgt, label, logits, wsf, Xc);
  k_stats<<<1, 256, 0, stream>>>(iter_p, wsf);
  k_main<<<NBLK, 256, 0, stream>>>(Xc, label, logits, wsf, out);
}